// Round 1
// baseline (211.737 us; speedup 1.0000x reference)
//
#include <hip/hip_runtime.h>
#include <hip/hip_fp16.h>
#include <math.h>

#define HP   2080          // padded height (2048 + 2*16)
#define WP   2080          // padded width
#define MARG 16
#define HOUT 2048
#define WOUT 2048
#define RAD  16            // truncation radius; tail mass ~2e-7

// 16x16 binning: a 64x64 output tile needs canvas rows 64t..64t+95 = bins 4t..4t+5 exactly
#define BT   130           // 2080/16 bins per dim
#define NB   (BT * BT)     // 16900 bins
#define CAP  160           // mean ~69 records/bin (Poisson, 11 sigma headroom)

#define AST  99            // LDS frame stride (98 cols + 1 pad -> odd stride, 2-way banks max)
#define BST  65            // hconv-result stride (64 + 1 pad -> conflict-free)

// exact discrete tap via Poisson summation: g[n] = sqrt(pi/200)*exp(-pi^2 n^2/200)
__device__ __forceinline__ void make_weights(float* wreg) {
#pragma unroll
    for (int t = 0; t <= RAD; ++t)
        wreg[t] = 0.12533141373155003f * __expf(-0.04934802200544679f * (float)(t * t));
}

// ---------------------------------------------------------------------------
// pass 1: direct-atomic binning at 16x16 granularity. ~67 records/bin means
// cursor atomics are nearly uncontended (vs 256-way in the old reservation
// scheme); no LDS histogram, no multi-phase block structure.
// Halo-dup: a point whose cell row%16==15 (col%16==15) is duplicated into the
// bin below (right) with lr1=0 (lc1=0), so each bin's records can cover the
// bin's own pixels exclusively (clipped splat in pass 2).
// ---------------------------------------------------------------------------
__global__ __launch_bounds__(256) void scatter16(const float2* __restrict__ pos,
                                                 const float* __restrict__ inten,
                                                 int* __restrict__ cursor,   // [NB], zeroed
                                                 ushort4* __restrict__ bins,
                                                 int n) {
    int i = blockIdx.x * 256 + threadIdx.x;
    const int stride = gridDim.x * 256;
    for (; i < n; i += stride) {
        float2 p = pos[i];
        float I  = inten[i];
        float px = p.x + MARG, py = p.y + MARG;
        int col = (int)floorf(px), row = (int)floorf(py);
        row = min(max(row, 0), HP - 1);
        col = min(max(col, 0), WP - 1);
        float dy = py - (float)row, dx = px - (float)col;
        ushort4 rec;
        rec.y = __half_as_ushort(__float2half(dx));
        rec.z = __half_as_ushort(__float2half(dy));
        rec.w = __half_as_ushort(__float2half(I));
        const int tr = row >> 4, tc = col >> 4;
        const int er = ((row & 15) == 15) ? 1 : 0;
        const int ec = ((col & 15) == 15) ? 1 : 0;
        for (int dr = 0; dr <= er; ++dr) {
            int br = tr + dr;
            if (br >= BT) break;
            int lr1 = row - (br << 4) + 1;          // 0..16 (0 only for dups)
            for (int dc = 0; dc <= ec; ++dc) {
                int bc = tc + dc;
                if (bc >= BT) break;
                int lc1 = col - (bc << 4) + 1;      // 0..16
                int bin = br * BT + bc;
                rec.x = (unsigned short)((lr1 << 5) | lc1);
                int idx = atomicAdd(&cursor[bin], 1);
                if (idx < CAP) bins[(size_t)bin * CAP + idx] = rec;
            }
        }
    }
}

// ---------------------------------------------------------------------------
// pass 2 (fused): per 64x64 output tile -> splat 6x6 bins into a 98x98 LDS
// frame (canvas rows/cols 64t-1 .. 64t+96), hconv into a 96x64 LDS buffer,
// vconv, store. Canvas and temp never exist in HBM.
//
// Frame coords: frame index f <-> canvas row 64t + f - 1. Bin beta (0..5)
// owns frame rows 16*beta+1 .. 16*beta+16. A record (bin beta, lr1) sits at
// fr = 16*beta + lr1; tap fr is owned iff lr1>=1, tap fr+1 iff lr1<=15
// (the complementary taps are covered by the neighbor bin's copy/original).
// ---------------------------------------------------------------------------
__global__ __launch_bounds__(512) void splat_conv(const ushort4* __restrict__ bins,
                                                  const int* __restrict__ cursor,
                                                  float* __restrict__ out) {
    __shared__ float A[98 * AST];   // 38.8 KB splat frame
    __shared__ float B[96 * BST];   // 25.0 KB hconv result (rows = canvas 64t..64t+95)
    const int tid = threadIdx.x;
    const int tI  = blockIdx.y, tJ = blockIdx.x;

    for (int i = tid; i < 98 * AST; i += 512) A[i] = 0.0f;
    __syncthreads();

    // ---- splat: 36 bins distributed over 8 waves ----
    const int wave = tid >> 6, lane = tid & 63;
    for (int b = wave; b < 36; b += 8) {
        const int bR = b / 6, bC = b % 6;                      // 0..5
        const int bin = (4 * tI + bR) * BT + (4 * tJ + bC);    // always in range
        const int cnt = min(cursor[bin], CAP);
        const ushort4* bp = bins + (size_t)bin * CAP;
        const int rb = bR << 4, cb = bC << 4;
        for (int i = lane; i < cnt; i += 64) {
            ushort4 r = bp[i];
            int lr1 = r.x >> 5, lc1 = r.x & 31;                // 0..16
            float dx = __half2float(__ushort_as_half(r.y));
            float dy = __half2float(__ushort_as_half(r.z));
            float I  = __half2float(__ushort_as_half(r.w));
            int fr = rb + lr1, fc = cb + lc1;
            float wy0 = (1.0f - dy) * I, wy1 = dy * I;
            float wx0 = 1.0f - dx,       wx1 = dx;
            if (lr1 >= 1) {
                if (lc1 >= 1)  atomicAdd(&A[fr * AST + fc],       wy0 * wx0);
                if (lc1 <= 15) atomicAdd(&A[fr * AST + fc + 1],   wy0 * wx1);
            }
            if (lr1 <= 15) {
                if (lc1 >= 1)  atomicAdd(&A[(fr + 1) * AST + fc],     wy1 * wx0);
                if (lc1 <= 15) atomicAdd(&A[(fr + 1) * AST + fc + 1], wy1 * wx1);
            }
        }
    }
    __syncthreads();

    float wreg[RAD + 1];
    make_weights(wreg);

    // ---- hconv: B[j][x] = sum_d w[|d|] * A[j+1][x+1+d+16? -> window o+1..o+40] ----
    // thread -> (row j = tid>>3 [+64], col octet o = (tid&7)*8); 96x64 outputs
    for (int half = 0; half < 2; ++half) {
        const int j = (tid >> 3) + (half << 6);
        if (j < 96) {
            const int o = (tid & 7) << 3;
            const float* Ar = &A[(j + 1) * AST + o + 1];
            float Wf[40];
#pragma unroll
            for (int t = 0; t < 40; ++t) Wf[t] = Ar[t];
            float a[8] = {0, 0, 0, 0, 0, 0, 0, 0};
#pragma unroll
            for (int t = 0; t < 40; ++t) {
                float v = Wf[t];
#pragma unroll
                for (int k = 0; k < 8; ++k)
                    if (t >= k && t <= k + 32)
                        a[k] += v * wreg[(t - k - 16 < 0) ? (k + 16 - t) : (t - k - 16)];
            }
            float* Br = &B[j * BST + o];
#pragma unroll
            for (int k = 0; k < 8; ++k) Br[k] = a[k];
        }
    }
    __syncthreads();

    // ---- vconv + store: out row (64*tI + y0 + k), thread covers 8 rows x 1 col ----
    const int lx = tid & 63;
    const int y0 = (tid >> 6) << 3;      // 0,8,...,56
    float Wf[40];
#pragma unroll
    for (int t = 0; t < 40; ++t) Wf[t] = B[(y0 + t) * BST + lx];
    float a[8] = {0, 0, 0, 0, 0, 0, 0, 0};
#pragma unroll
    for (int t = 0; t < 40; ++t) {
        float v = Wf[t];
#pragma unroll
        for (int k = 0; k < 8; ++k)
            if (t >= k && t <= k + 32)
                a[k] += v * wreg[(t - k - 16 < 0) ? (k + 16 - t) : (t - k - 16)];
    }
    const int orow = (tI << 6) + y0, ocol = (tJ << 6) + lx;
#pragma unroll
    for (int k = 0; k < 8; ++k)
        out[(size_t)(orow + k) * WOUT + ocol] = a[k];
}

extern "C" void kernel_launch(void* const* d_in, const int* in_sizes, int n_in,
                              void* d_out, int out_size, void* d_ws, size_t ws_size,
                              hipStream_t stream) {
    const float2* pos   = (const float2*)d_in[0];   // (N,2) as (x,y)
    const float*  inten = (const float*)d_in[1];
    int n = in_sizes[1];

    ushort4* bins   = (ushort4*)d_ws;                                   // 16900*160*8 = 21.6 MB
    int*     cursor = (int*)((char*)d_ws + (size_t)NB * CAP * sizeof(ushort4)); // 67.6 KB

    hipMemsetAsync(cursor, 0, NB * sizeof(int), stream);
    scatter16<<<2048, 256, 0, stream>>>(pos, inten, cursor, bins, n);
    splat_conv<<<dim3(WOUT / 64, HOUT / 64), 512, 0, stream>>>(bins, cursor, (float*)d_out);
}